// Round 4
// baseline (164.176 us; speedup 1.0000x reference)
//
#include <hip/hip_runtime.h>
#include <hip/hip_bf16.h>

typedef short short8 __attribute__((ext_vector_type(8)));
typedef float floatx4 __attribute__((ext_vector_type(4)));
typedef unsigned uint4v __attribute__((ext_vector_type(4)));

#define HWSZ 16384   // 128*128
#define WD 128
#define CD 64
#define OD 64
#define OSTR 132     // fp32 epilogue stride (16B-aligned)
#define XTROW (130 * 64)          // shorts per (b,h) row of xt: 130 w-slots x 64 c
#define WP_BYTES (9 * 64 * 64 * 2)
#define L2E2 2.8853900817779268f  // 2*log2(e)

__device__ __forceinline__ short f2bf(float f) {
    unsigned u = __builtin_bit_cast(unsigned, f);
    u += 0x7FFFu + ((u >> 16) & 1u);     // RNE
    return (short)(u >> 16);
}

__device__ __forceinline__ unsigned pack2bf(float a, float b) {
    __hip_bfloat162 h = __float22bfloat162_rn(float2{a, b});
    unsigned u;
    __builtin_memcpy(&u, &h, 4);
    return u;
}

__device__ __forceinline__ float bf2f(short s) {
    return __builtin_bit_cast(float, ((unsigned)(unsigned short)s) << 16);
}

// one-time repack: wgt[o][c][k] fp32 -> wp[k][o][c] bf16, scaled by 2
// (filter 2-2r folded as t = x*(1-r) against 2W; x2 exact in bf16)
__global__ void prepack_w(const float* __restrict__ wgt, unsigned short* __restrict__ wp) {
    int idx = blockIdx.x * 256 + threadIdx.x;     // 9*64*64 = 36864
    if (idx < 9 * 64 * 64) {
        int k = idx >> 12, o = (idx >> 6) & 63, c = idx & 63;
        wp[idx] = (unsigned short)f2bf(2.0f * wgt[o * 576 + c * 9 + k]);
    }
}

// transpose: x[b][c][h][w] fp32 -> xt[b][h][wslot][c] bf16, wslot = w+1,
// slots 0 and 129 zeroed (w halo). Conflict-free: LDS stride 33 dwords,
// lane-step = 1 row => bank step 1.
__global__ __launch_bounds__(256, 2)
void transpose_x(const float* __restrict__ x, unsigned short* __restrict__ xt) {
    __shared__ unsigned ld[128 * 33];
    const int tid = threadIdx.x;
    const int b = blockIdx.x >> 7;
    const int h = blockIdx.x & 127;
    const float* xr = x + (size_t)b * CD * HWSZ + h * WD;

    #pragma unroll
    for (int it = 0; it < 16; ++it) {
        int idx = it * 256 + tid;        // 0..4095
        int cd = idx >> 7;               // c-pair 0..31
        int w  = idx & 127;              // lanes sweep w: coalesced loads, bank-step 1 writes
        float a  = xr[(size_t)(2 * cd) * HWSZ + w];
        float b2 = xr[(size_t)(2 * cd + 1) * HWSZ + w];
        ld[w * 33 + cd] = pack2bf(a, b2);
    }
    __syncthreads();

    unsigned short* xo = xt + (size_t)(b * 128 + h) * XTROW;
    if (tid < 16) {                      // zero halo slots 0 and 129
        int slot = (tid >> 3) ? 129 : 0;
        int cq = tid & 7;
        *(uint4v*)&xo[slot * 64 + cq * 8] = (uint4v){0u, 0u, 0u, 0u};
    }
    #pragma unroll
    for (int it = 0; it < 4; ++it) {
        int idx = it * 256 + tid;        // 0..1023 dwordx4 stores
        int w = idx >> 3, cq = idx & 7;
        uint4v v;
        #pragma unroll
        for (int i = 0; i < 4; ++i) v[i] = ld[w * 33 + cq * 4 + i];
        *(uint4v*)&xo[(1 + w) * 64 + cq * 8] = v;   // contiguous 16B/lane: coalesced
    }
}

// main: no LDS / no barriers in the K-loop. A/B frags via global dwordx4
// (xt rows L2/L3-hot, wp 74KB L1/L2-hot). LDS only for epilogue transpose.
__global__ __launch_bounds__(256, 4)
void paka_main(const float* __restrict__ gc, const float* __restrict__ gs,
               const unsigned short* __restrict__ wp,
               const unsigned short* __restrict__ xt, float* __restrict__ out)
{
    __shared__ float lo[64 * OSTR];

    const int tid  = threadIdx.x;
    const int wave = tid >> 6;
    const int lane = tid & 63;
    const int b = blockIdx.x >> 7;
    const int h = blockIdx.x & 127;

    const float* gcb = gc + (size_t)b * CD * HWSZ;
    const float* gsb = gs + (size_t)b * 9 * HWSZ;

    const int row = lane & 15;
    const int q   = lane >> 4;
    const int mt0 = wave * 2;

    // eg = exp2(2log2e * gc[c][h][p]); p = (mt0+mt)*16+row, c = ks*32+q*8+j
    // per instr: 4 q-segments x 64B -> dense
    float eg[2][2][8];
    #pragma unroll
    for (int mt = 0; mt < 2; ++mt) {
        int p = (mt0 + mt) * 16 + row;
        #pragma unroll
        for (int ks = 0; ks < 2; ++ks)
            #pragma unroll
            for (int j = 0; j < 8; ++j) {
                int c = ks * 32 + q * 8 + j;
                eg[mt][ks][j] = __builtin_amdgcn_exp2f(gcb[(size_t)c * HWSZ + h * WD + p] * L2E2);
            }
    }

    floatx4 acc[2][4];
    #pragma unroll
    for (int i = 0; i < 2; ++i)
        #pragma unroll
        for (int n = 0; n < 4; ++n)
            acc[i][n] = (floatx4){0.f, 0.f, 0.f, 0.f};

    #pragma unroll
    for (int dh = 0; dh < 3; ++dh) {
        const int hh = h + dh - 1;
        if ((unsigned)hh >= 128u) continue;       // uniform: zero-padded taps

        const unsigned short* xr = xt + (size_t)(b * 128 + hh) * XTROW;

        // es for this dh's 3 taps (6 regs, recomputed per dh to cap VGPRs)
        float esd[3][2];
        #pragma unroll
        for (int dw = 0; dw < 3; ++dw)
            #pragma unroll
            for (int mt = 0; mt < 2; ++mt) {
                int p = (mt0 + mt) * 16 + row;
                esd[dw][mt] = __builtin_amdgcn_exp2f(gsb[(dh * 3 + dw) * HWSZ + h * WD + p] * L2E2);
            }

        #pragma unroll
        for (int dw = 0; dw < 3; ++dw) {
            const int k = dh * 3 + dw;
            #pragma unroll
            for (int ks = 0; ks < 2; ++ks) {
                // A raw: 16B/lane, 16 rows x 64B dense segments
                short8 raw[2];
                #pragma unroll
                for (int mt = 0; mt < 2; ++mt) {
                    int wslot = (mt0 + mt) * 16 + row + dw;   // p + dw (halo layout)
                    raw[mt] = *(const short8*)&xr[(size_t)wslot * 64 + ks * 32 + q * 8];
                }
                // B frags from wp[k][o][c]
                short8 bv[4];
                #pragma unroll
                for (int nt = 0; nt < 4; ++nt)
                    bv[nt] = *(const short8*)&wp[k * 4096 + (nt * 16 + row) * 64 + ks * 32 + q * 8];

                short8 af[2];
                #pragma unroll
                for (int mt = 0; mt < 2; ++mt) {
                    float es = esd[dw][mt];
                    #pragma unroll
                    for (int jj = 0; jj < 4; ++jj) {
                        float d0 = fmaf(eg[mt][ks][2 * jj],     es, 1.0f);
                        float d1 = fmaf(eg[mt][ks][2 * jj + 1], es, 1.0f);
                        float r0 = __builtin_amdgcn_rcpf(d0);
                        float r1 = __builtin_amdgcn_rcpf(d1);
                        float x0 = bf2f(raw[mt][2 * jj]);
                        float x1 = bf2f(raw[mt][2 * jj + 1]);
                        float t0 = fmaf(-x0, r0, x0);         // x*(1-r), W carries the 2x
                        float t1 = fmaf(-x1, r1, x1);
                        ((unsigned*)&af[mt])[jj] = pack2bf(t0, t1);
                    }
                }
                #pragma unroll
                for (int nt = 0; nt < 4; ++nt) {
                    acc[0][nt] = __builtin_amdgcn_mfma_f32_16x16x32_bf16(af[0], bv[nt], acc[0][nt], 0, 0, 0);
                    acc[1][nt] = __builtin_amdgcn_mfma_f32_16x16x32_bf16(af[1], bv[nt], acc[1][nt], 0, 0, 0);
                }
            }
        }
    }

    // epilogue: D col(=o)=lane&15, rowD(=p)=(lane>>4)*4+reg; transpose via LDS
    #pragma unroll
    for (int i = 0; i < 2; ++i) {
        int prow = (mt0 + i) * 16 + q * 4;
        #pragma unroll
        for (int nt = 0; nt < 4; ++nt) {
            int o = nt * 16 + row;
            #pragma unroll
            for (int r = 0; r < 4; ++r)
                lo[o * OSTR + prow + r] = acc[i][nt][r];
        }
    }
    __syncthreads();

    float* outb = out + ((size_t)b * OD) * HWSZ + h * WD;
    #pragma unroll
    for (int it = 0; it < 8; ++it) {
        int idx = it * 256 + tid;
        int o = idx >> 5, p4 = (idx & 31) * 4;
        *(floatx4*)&outb[(size_t)o * HWSZ + p4] = *(const floatx4*)&lo[o * OSTR + p4];
    }
}

// ---------------- fallback (R3 kernel, wgt path only) for small ws ----------------
#define XSTR 72
__global__ __launch_bounds__(256, 3)
void paka_fallback(const float* __restrict__ x, const float* __restrict__ gc,
                   const float* __restrict__ gs, const float* __restrict__ wgt,
                   float* __restrict__ out)
{
    __shared__ union {
        struct { short xl[130 * XSTR]; short wl[3][64 * XSTR]; } s;
        float o[64 * OSTR];
    } lds;
    const int tid  = threadIdx.x;
    const int wave = tid >> 6;
    const int lane = tid & 63;
    const int b = blockIdx.x >> 7;
    const int h = blockIdx.x & 127;
    const float* xb  = x  + (size_t)b * CD * HWSZ;
    const float* gcb = gc + (size_t)b * CD * HWSZ;
    const float* gsb = gs + (size_t)b * 9 * HWSZ;
    const int row = lane & 15, q = lane >> 4, mt0 = wave * 2;
    float eg[2][2][8];
    #pragma unroll
    for (int mt = 0; mt < 2; ++mt) {
        int p = (mt0 + mt) * 16 + row;
        #pragma unroll
        for (int ks = 0; ks < 2; ++ks)
            #pragma unroll
            for (int j = 0; j < 8; ++j)
                eg[mt][ks][j] = __builtin_amdgcn_exp2f(gcb[(size_t)(ks * 32 + q * 8 + j) * HWSZ + h * WD + p] * L2E2);
    }
    float esv[9][2];
    #pragma unroll
    for (int k = 0; k < 9; ++k)
        #pragma unroll
        for (int mt = 0; mt < 2; ++mt)
            esv[k][mt] = __builtin_amdgcn_exp2f(gsb[k * HWSZ + h * WD + (mt0 + mt) * 16 + row] * L2E2);
    if (tid < 32) *(unsigned*)&lds.s.xl[0 * XSTR + tid * 2] = 0u;
    else if (tid < 64) *(unsigned*)&lds.s.xl[129 * XSTR + (tid - 32) * 2] = 0u;
    floatx4 acc[2][4];
    #pragma unroll
    for (int i = 0; i < 2; ++i)
        #pragma unroll
        for (int n = 0; n < 4; ++n) acc[i][n] = (floatx4){0.f, 0.f, 0.f, 0.f};
    #pragma unroll
    for (int dh = 0; dh < 3; ++dh) {
        const int hh = h + dh - 1;
        if ((unsigned)hh >= 128u) continue;
        __syncthreads();
        #pragma unroll
        for (int it = 0; it < 48; ++it) {
            int idx = it * 256 + tid;
            int dw = idx >> 12, o = (idx >> 6) & 63, c = idx & 63;
            lds.s.wl[dw][o * XSTR + c] = f2bf(wgt[o * 576 + c * 9 + dh * 3 + dw]);
        }
        #pragma unroll
        for (int it = 0; it < 4; ++it) {
            int idx = it * 256 + tid;
            int cp = idx >> 5, p4 = (idx & 31) * 4;
            const float* x0 = xb + (size_t)(2 * cp) * HWSZ + hh * WD + p4;
            floatx4 a = *(const floatx4*)x0;
            floatx4 c4 = *(const floatx4*)(x0 + HWSZ);
            #pragma unroll
            for (int i = 0; i < 4; ++i)
                *(unsigned*)&lds.s.xl[(p4 + i + 1) * XSTR + 2 * cp] = pack2bf(a[i], c4[i]);
        }
        __syncthreads();
        #pragma unroll
        for (int dw = 0; dw < 3; ++dw) {
            const int k = dh * 3 + dw;
            #pragma unroll
            for (int ks = 0; ks < 2; ++ks) {
                short8 af[2];
                #pragma unroll
                for (int mt = 0; mt < 2; ++mt) {
                    int wslot = (mt0 + mt) * 16 + row + dw;
                    short8 raw = *(const short8*)&lds.s.xl[wslot * XSTR + ks * 32 + q * 8];
                    float es = esv[k][mt];
                    #pragma unroll
                    for (int jj = 0; jj < 4; ++jj) {
                        float d0 = fmaf(eg[mt][ks][2 * jj],     es, 1.0f);
                        float d1 = fmaf(eg[mt][ks][2 * jj + 1], es, 1.0f);
                        float r0 = __builtin_amdgcn_rcpf(d0);
                        float r1 = __builtin_amdgcn_rcpf(d1);
                        float x20 = bf2f(raw[2 * jj]);     x20 += x20;
                        float x21 = bf2f(raw[2 * jj + 1]); x21 += x21;
                        float t0 = fmaf(-x20, r0, x20);
                        float t1 = fmaf(-x21, r1, x21);
                        ((unsigned*)&af[mt])[jj] = pack2bf(t0, t1);
                    }
                }
                #pragma unroll
                for (int nt = 0; nt < 4; ++nt) {
                    short8 bv = *(const short8*)&lds.s.wl[dw][(nt * 16 + row) * XSTR + ks * 32 + q * 8];
                    acc[0][nt] = __builtin_amdgcn_mfma_f32_16x16x32_bf16(af[0], bv, acc[0][nt], 0, 0, 0);
                    acc[1][nt] = __builtin_amdgcn_mfma_f32_16x16x32_bf16(af[1], bv, acc[1][nt], 0, 0, 0);
                }
            }
        }
    }
    __syncthreads();
    #pragma unroll
    for (int i = 0; i < 2; ++i) {
        int prow = (mt0 + i) * 16 + q * 4;
        #pragma unroll
        for (int nt = 0; nt < 4; ++nt) {
            int o = nt * 16 + row;
            #pragma unroll
            for (int r = 0; r < 4; ++r)
                lds.o[o * OSTR + prow + r] = acc[i][nt][r];
        }
    }
    __syncthreads();
    float* outb = out + ((size_t)b * OD) * HWSZ + h * WD;
    #pragma unroll
    for (int it = 0; it < 8; ++it) {
        int idx = it * 256 + tid;
        int o = idx >> 5, p4 = (idx & 31) * 4;
        *(floatx4*)&outb[(size_t)o * HWSZ + p4] = *(const floatx4*)&lds.o[o * OSTR + p4];
    }
}

extern "C" void kernel_launch(void* const* d_in, const int* in_sizes, int n_in,
                              void* d_out, int out_size, void* d_ws, size_t ws_size,
                              hipStream_t stream) {
    const float* x   = (const float*)d_in[0];
    const float* gcp = (const float*)d_in[1];
    const float* gsp = (const float*)d_in[2];
    const float* wgt = (const float*)d_in[3];
    float* out = (float*)d_out;

    const size_t xt_bytes = (size_t)8 * 128 * XTROW * 2;   // ~16.6 MB
    const size_t need = WP_BYTES + xt_bytes;
    if (ws_size >= need) {
        unsigned short* wp = (unsigned short*)d_ws;
        unsigned short* xt = (unsigned short*)((char*)d_ws + WP_BYTES);
        prepack_w<<<dim3(144), dim3(256), 0, stream>>>(wgt, wp);
        transpose_x<<<dim3(1024), dim3(256), 0, stream>>>(x, xt);
        paka_main<<<dim3(1024), dim3(256), 0, stream>>>(gcp, gsp, wp, xt, out);
    } else {
        paka_fallback<<<dim3(1024), dim3(256), 0, stream>>>(x, gcp, gsp, wgt, out);
    }
}